// Round 13
// baseline (238.089 us; speedup 1.0000x reference)
//
#include <hip/hip_runtime.h>
#include <hip/hip_fp16.h>

// ---------------------------------------------------------------------------
// GCN: out = (relu(conv2(relu(conv1(x@We+be)))))@Wo + bo
// GEMMs: fp16 MFMA 16x16x32, fp32 accum. Conv GEMMs write t pre-scaled by
// dinv[row], so agg = t_s[node] + sum t_s[col[j]]; out = relu(b + dinv*agg).
// CSR build: bucket edges by dst-range (RS=100) -> scan -> per-bucket LDS
// histogram + contiguous-window scatter.
// ---------------------------------------------------------------------------

#define WS_ALIGN(x) (((x) + 255) & ~(size_t)255)
#define RS 100      // nodes per bucket
#define BCHUNK 8192 // edges per block in bucket pass

typedef _Float16 f16x8 __attribute__((ext_vector_type(8)));
typedef float f32x4 __attribute__((ext_vector_type(4)));

// flag=1 => edge_index is int64, flag=0 => int32
__global__ void detect_i64_kernel(const unsigned* __restrict__ p, int* __restrict__ flag) {
    __shared__ int any;
    if (threadIdx.x == 0) any = 0;
    __syncthreads();
    int nz = 0;
    for (int i = threadIdx.x; i < 2048; i += blockDim.x)
        nz |= (p[2 * i + 1] != 0u) ? 1 : 0;
    if (nz) atomicOr(&any, 1);
    __syncthreads();
    if (threadIdx.x == 0) *flag = (any == 0) ? 1 : 0;
}

__global__ void zero_u32_kernel(unsigned* __restrict__ a, int n) {
    int i = blockIdx.x * blockDim.x + threadIdx.x;
    if (i < n) a[i] = 0u;
}

// Bucket edges into nbuck dst-range buckets. Two passes over the block's edge
// chunk (2nd pass L2-hot): LDS count -> one global atomicAdd per bucket ->
// LDS-cursor placement. No per-thread register arrays.
__global__ __launch_bounds__(256) void bucket_kernel(
    const void* __restrict__ ep, const int* __restrict__ flag,
    unsigned* __restrict__ bkt, unsigned* __restrict__ bfill_pad,
    int E, int nbuck, int capB) {
    __shared__ unsigned lcnt[512];
    __shared__ unsigned gcur[512];
    const int tid = threadIdx.x;
    for (int i = tid; i < nbuck; i += 256) lcnt[i] = 0;
    __syncthreads();
    const int base = blockIdx.x * BCHUNK;
    const int end = min(base + BCHUNK, E);
    const int i64 = *flag;
    // pass 1: count
    if (i64) {
        const long long* p = (const long long*)ep;
        for (int i = base + tid; i < end; i += 256) {
            int d = (int)p[(size_t)E + i];
            atomicAdd(&lcnt[d / RS], 1u);
        }
    } else {
        const int* p = (const int*)ep;
        for (int i = base + tid; i < end; i += 256) {
            int d = p[(size_t)E + i];
            atomicAdd(&lcnt[d / RS], 1u);
        }
    }
    __syncthreads();
    for (int i = tid; i < nbuck; i += 256)
        gcur[i] = atomicAdd(&bfill_pad[i << 4], lcnt[i]);
    __syncthreads();
    // pass 2: place (re-read edges, L2-hot)
    if (i64) {
        const long long* p = (const long long*)ep;
        for (int i = base + tid; i < end; i += 256) {
            int s = (int)p[i];
            int d = (int)p[(size_t)E + i];
            int part = d / RS;
            int ld = d - part * RS;
            unsigned pos = atomicAdd(&gcur[part], 1u);
            if (pos < (unsigned)capB)
                bkt[(size_t)part * capB + pos] = ((unsigned)ld << 24) | (unsigned)s;
        }
    } else {
        const int* p = (const int*)ep;
        for (int i = base + tid; i < end; i += 256) {
            int s = p[i];
            int d = p[(size_t)E + i];
            int part = d / RS;
            int ld = d - part * RS;
            unsigned pos = atomicAdd(&gcur[part], 1u);
            if (pos < (unsigned)capB)
                bkt[(size_t)part * capB + pos] = ((unsigned)ld << 24) | (unsigned)s;
        }
    }
}

// Exclusive scan of bucket counts -> ebase; rowp[n] = total.
__global__ __launch_bounds__(512) void bucket_scan_kernel(
    const unsigned* __restrict__ bfill_pad, unsigned* __restrict__ ebase,
    int* __restrict__ rowp, int nbuck, int capB, int n) {
    __shared__ unsigned lds[512];
    const int tid = threadIdx.x;
    unsigned v = 0;
    if (tid < nbuck) {
        v = bfill_pad[tid << 4];
        if (v > (unsigned)capB) v = capB;
    }
    lds[tid] = v;
    __syncthreads();
    for (int off = 1; off < 512; off <<= 1) {
        unsigned add = (tid >= off) ? lds[tid - off] : 0;
        __syncthreads();
        lds[tid] += add;
        __syncthreads();
    }
    if (tid < nbuck) ebase[tid] = lds[tid] - v;  // exclusive
    if (tid == 511) rowp[n] = (int)lds[511];
}

// One block per bucket: LDS hist -> rowp/dinv; scatter col into the bucket's
// contiguous CSR window.
__global__ __launch_bounds__(256) void csr_from_bucket_kernel(
    const unsigned* __restrict__ bkt, const unsigned* __restrict__ bfill_pad,
    const unsigned* __restrict__ ebase,
    int* __restrict__ rowp, float* __restrict__ dinv, int* __restrict__ col,
    int capB, int n) {
    __shared__ unsigned hist[RS];
    __shared__ int fillo[RS];
    const int p = blockIdx.x;
    const int tid = threadIdx.x;
    for (int i = tid; i < RS; i += 256) hist[i] = 0;
    __syncthreads();
    unsigned cnt = bfill_pad[p << 4];
    if (cnt > (unsigned)capB) cnt = capB;
    const unsigned* bp = bkt + (size_t)p * capB;
    for (unsigned e = tid; e < cnt; e += 256)
        atomicAdd(&hist[bp[e] >> 24], 1u);
    __syncthreads();
    if (tid == 0) {
        int run = (int)ebase[p];
        for (int i = 0; i < RS; ++i) { fillo[i] = run; run += (int)hist[i]; }
    }
    __syncthreads();
    const int lo = p * RS;
    for (int i = tid; i < RS; i += 256) {
        int node = lo + i;
        if (node < n) {
            rowp[node] = fillo[i];
            dinv[node] = rsqrtf((float)(hist[i] + 1u));
        }
    }
    for (unsigned e = tid; e < cnt; e += 256) {
        unsigned u = bp[e];
        int ld = (int)(u >> 24);
        int pos = atomicAdd(&fillo[ld], 1);
        col[pos] = (int)(u & 0xFFFFFFu);
    }
}

// out[i][:] = relu( bias + dinv[i]*( t_s[i][:] + sum_j t_s[col[j]][:] ) )
// t_s fp16 pre-scaled by dinv[row]. 32 lanes/node, 8-wide gather unroll.
__global__ __launch_bounds__(256) void agg_pull_kernel(
    const int* __restrict__ rowp, const int* __restrict__ col,
    const float* __restrict__ dinv, const __half* __restrict__ t,
    const float* __restrict__ bias, __half* __restrict__ out, int n) {
    int node = blockIdx.x * 8 + (threadIdx.x >> 5);
    int lane = threadIdx.x & 31;
    if (node >= n) return;
    const uint2* T = (const uint2*)t;
    int j0 = rowp[node], j1 = rowp[node + 1];
    float dn = dinv[node];

    // self term: t_s[node] (already dinv*t)
    uint2 sraw = T[(size_t)node * 32 + lane];
    float2 s01 = __half22float2(*(const __half2*)&sraw.x);
    float2 s23 = __half22float2(*(const __half2*)&sraw.y);
    float4 acc = make_float4(s01.x, s01.y, s23.x, s23.y);

    int j = j0;
    for (; j + 7 < j1; j += 8) {
        int c[8];
        uint2 r[8];
#pragma unroll
        for (int k = 0; k < 8; ++k) c[k] = __builtin_nontemporal_load(col + j + k);
#pragma unroll
        for (int k = 0; k < 8; ++k) r[k] = T[(size_t)c[k] * 32 + lane];
#pragma unroll
        for (int k = 0; k < 8; ++k) {
            float2 f01 = __half22float2(*(const __half2*)&r[k].x);
            float2 f23 = __half22float2(*(const __half2*)&r[k].y);
            acc.x += f01.x; acc.y += f01.y; acc.z += f23.x; acc.w += f23.y;
        }
    }
    for (; j + 3 < j1; j += 4) {
        int c[4];
        uint2 r[4];
#pragma unroll
        for (int k = 0; k < 4; ++k) c[k] = __builtin_nontemporal_load(col + j + k);
#pragma unroll
        for (int k = 0; k < 4; ++k) r[k] = T[(size_t)c[k] * 32 + lane];
#pragma unroll
        for (int k = 0; k < 4; ++k) {
            float2 f01 = __half22float2(*(const __half2*)&r[k].x);
            float2 f23 = __half22float2(*(const __half2*)&r[k].y);
            acc.x += f01.x; acc.y += f01.y; acc.z += f23.x; acc.w += f23.y;
        }
    }
    for (; j < j1; ++j) {
        int c = __builtin_nontemporal_load(col + j);
        uint2 raw = T[(size_t)c * 32 + lane];
        float2 f01 = __half22float2(*(const __half2*)&raw.x);
        float2 f23 = __half22float2(*(const __half2*)&raw.y);
        acc.x += f01.x; acc.y += f01.y; acc.z += f23.x; acc.w += f23.y;
    }

    float4 b = ((const float4*)bias)[lane];
    float ox = fmaxf(fmaf(acc.x, dn, b.x), 0.f);
    float oy = fmaxf(fmaf(acc.y, dn, b.y), 0.f);
    float oz = fmaxf(fmaf(acc.z, dn, b.z), 0.f);
    float ow = fmaxf(fmaf(acc.w, dn, b.w), 0.f);
    __half2 h01 = __floats2half2_rn(ox, oy);
    __half2 h23 = __floats2half2_rn(oz, ow);
    uint2 packed;
    packed.x = *(unsigned*)&h01;
    packed.y = *(unsigned*)&h23;
    ((uint2*)(out + (size_t)node * 128))[lane] = packed;
}

// fp32 -> fp16, 8 elems/thread
__global__ void f32_to_f16_kernel(const float* __restrict__ in, __half* __restrict__ out, int n8) {
    int i = blockIdx.x * blockDim.x + threadIdx.x;
    if (i >= n8) return;
    const float4* in4 = (const float4*)in;
    float4 v0 = in4[2 * i], v1 = in4[2 * i + 1];
    __half2 h0 = __floats2half2_rn(v0.x, v0.y);
    __half2 h1 = __floats2half2_rn(v0.z, v0.w);
    __half2 h2 = __floats2half2_rn(v1.x, v1.y);
    __half2 h3 = __floats2half2_rn(v1.z, v1.w);
    uint4 p;
    p.x = *(unsigned*)&h0; p.y = *(unsigned*)&h1;
    p.z = *(unsigned*)&h2; p.w = *(unsigned*)&h3;
    *(uint4*)(out + (size_t)i * 8) = p;
}

// Build fragment-ready W: Wf[((c0*4+ks)*64+lane)*8+j] = f16(W[ks*32+(lane>>4)*8+j][c0*16+(lane&15)])
__global__ void wfrag_kernel(const float* __restrict__ W, __half* __restrict__ Wf, int ncol) {
    int t = blockIdx.x * blockDim.x + threadIdx.x;
    int total = (ncol >> 4) * 4 * 64;
    if (t >= total) return;
    int lane = t & 63;
    int ks = (t >> 6) & 3;
    int c0 = t >> 8;
    int colw = c0 * 16 + (lane & 15);
    int k0 = ks * 32 + ((lane >> 4) << 3);
    __half vals[8];
#pragma unroll
    for (int j = 0; j < 8; ++j) vals[j] = __float2half(W[(size_t)(k0 + j) * ncol + colw]);
    *(uint4*)(Wf + (size_t)t * 8) = *(uint4*)vals;
}

// C[n,ncol] = A[n,128](f16) @ W[128,ncol] (+bias) (*rowscale). MFMA f16, fp32 accum.
__global__ __launch_bounds__(256) void gemm_mfma_kernel(
    const __half* __restrict__ A, const __half* __restrict__ Wf,
    const float* __restrict__ bias, const float* __restrict__ rowscale,
    void* __restrict__ C, int n, int ncol, int c_fp32) {
    const int wave = threadIdx.x >> 6;
    const int lane = threadIdx.x & 63;
    const int row0 = blockIdx.x * 64 + wave * 16;
    int ar = row0 + (lane & 15);
    if (ar >= n) ar = n - 1;
    const __half* abase = A + (size_t)ar * 128 + ((lane >> 4) << 3);
    f16x8 a0 = *(const f16x8*)(abase);
    f16x8 a1 = *(const f16x8*)(abase + 32);
    f16x8 a2 = *(const f16x8*)(abase + 64);
    f16x8 a3 = *(const f16x8*)(abase + 96);
    const int ncc = ncol >> 4;
    const int cic = lane & 15;
    const int rbase = (lane >> 4) << 2;
    float rs[4];
#pragma unroll
    for (int r = 0; r < 4; ++r) {
        int row = row0 + rbase + r;
        rs[r] = (rowscale && row < n) ? rowscale[row] : 1.f;
    }
    for (int c0 = 0; c0 < ncc; ++c0) {
        const f16x8* wf = (const f16x8*)Wf + (size_t)c0 * 256 + lane;
        f32x4 acc = {0.f, 0.f, 0.f, 0.f};
        acc = __builtin_amdgcn_mfma_f32_16x16x32_f16(a0, wf[0],   acc, 0, 0, 0);
        acc = __builtin_amdgcn_mfma_f32_16x16x32_f16(a1, wf[64],  acc, 0, 0, 0);
        acc = __builtin_amdgcn_mfma_f32_16x16x32_f16(a2, wf[128], acc, 0, 0, 0);
        acc = __builtin_amdgcn_mfma_f32_16x16x32_f16(a3, wf[192], acc, 0, 0, 0);
        int colc = (c0 << 4) + cic;
        float bv = bias ? bias[colc] : 0.f;
#pragma unroll
        for (int r = 0; r < 4; ++r) {
            int row = row0 + rbase + r;
            if (row < n) {
                float v = acc[r] * rs[r] + bv;
                if (c_fp32) ((float*)C)[(size_t)row * ncol + colc] = v;
                else        ((__half*)C)[(size_t)row * ncol + colc] = __float2half(v);
            }
        }
    }
}

extern "C" void kernel_launch(void* const* d_in, const int* in_sizes, int n_in,
                              void* d_out, int out_size, void* d_ws, size_t ws_size,
                              hipStream_t stream) {
    const float* x  = (const float*)d_in[0];
    const void*  ei = d_in[1];
    const float* We = (const float*)d_in[2];
    const float* be = (const float*)d_in[3];
    const float* W1 = (const float*)d_in[4];
    const float* b1 = (const float*)d_in[5];
    const float* W2 = (const float*)d_in[6];
    const float* b2 = (const float*)d_in[7];
    const float* Wo = (const float*)d_in[8];
    const float* bo = (const float*)d_in[9];
    const int N = in_sizes[0] / 128;
    const int E = in_sizes[1] / 2;
    const int NC = in_sizes[9];                 // NUM_CLASS = 64
    const int nbuck = (N + RS - 1) / RS;        // 500 for N=50000 (<=512)
    const int capB = (E + nbuck - 1) / nbuck + 512;

    char* ws = (char*)d_ws;
    size_t off = 0;
    int*      flag = (int*)(ws + off);      off += 256;
    unsigned* bfil = (unsigned*)(ws + off); off += WS_ALIGN((size_t)nbuck * 64);
    unsigned* ebas = (unsigned*)(ws + off); off += WS_ALIGN((size_t)nbuck * 4);
    unsigned* bkt  = (unsigned*)(ws + off); off += WS_ALIGN((size_t)nbuck * capB * 4);
    float*    dinv = (float*)(ws + off);    off += WS_ALIGN((size_t)N * 4);
    int*      rowp = (int*)(ws + off);      off += WS_ALIGN((size_t)(N + 1) * 4);
    int*      colw = (int*)(ws + off);      off += WS_ALIGN((size_t)E * 4);
    __half*   WeF  = (__half*)(ws + off);   off += WS_ALIGN((size_t)128 * 128 * 2);
    __half*   W1F  = (__half*)(ws + off);   off += WS_ALIGN((size_t)128 * 128 * 2);
    __half*   W2F  = (__half*)(ws + off);   off += WS_ALIGN((size_t)128 * 128 * 2);
    __half*   WoF  = (__half*)(ws + off);   off += WS_ALIGN((size_t)128 * 64 * 2);
    __half*   xH   = (__half*)(ws + off);   off += WS_ALIGN((size_t)N * 128 * 2);
    __half*   hA   = (__half*)(ws + off);   off += WS_ALIGN((size_t)N * 128 * 2);
    __half*   tH   = (__half*)(ws + off);   off += WS_ALIGN((size_t)N * 128 * 2);

    const int nb_bucket = (E + BCHUNK - 1) / BCHUNK;
    const int nb_zero = (nbuck * 16 + 255) / 256;
    dim3 blk(256);

    // CSR build via buckets
    detect_i64_kernel<<<1, 256, 0, stream>>>((const unsigned*)ei, flag);
    zero_u32_kernel<<<nb_zero, blk, 0, stream>>>(bfil, nbuck * 16);
    bucket_kernel<<<nb_bucket, blk, 0, stream>>>(ei, flag, bkt, bfil, E, nbuck, capB);
    bucket_scan_kernel<<<1, 512, 0, stream>>>(bfil, ebas, rowp, nbuck, capB, N);
    csr_from_bucket_kernel<<<nbuck, blk, 0, stream>>>(bkt, bfil, ebas, rowp, dinv, colw, capB, N);

    // weight fragments + x fp16
    wfrag_kernel<<<8, 256, 0, stream>>>(We, WeF, 128);
    wfrag_kernel<<<8, 256, 0, stream>>>(W1, W1F, 128);
    wfrag_kernel<<<8, 256, 0, stream>>>(W2, W2F, 128);
    wfrag_kernel<<<4, 256, 0, stream>>>(Wo, WoF, NC);
    f32_to_f16_kernel<<<(N * 16 + 255) / 256, 256, 0, stream>>>(x, xH, N * 16);

    const int gemm_blocks = (N + 63) / 64;
    const int agg_blocks = (N + 7) / 8;

    // encoder: h0 = x@We + be -> hA (fp16)
    gemm_mfma_kernel<<<gemm_blocks, blk, 0, stream>>>(xH, WeF, be, nullptr, hA, N, 128, 0);
    // conv1: t1 = dinv*(h0@W1) -> tH ; a1 = relu(Agg(t1)+b1) -> hA
    gemm_mfma_kernel<<<gemm_blocks, blk, 0, stream>>>(hA, W1F, nullptr, dinv, tH, N, 128, 0);
    agg_pull_kernel<<<agg_blocks, blk, 0, stream>>>(rowp, colw, dinv, tH, b1, hA, N);
    // conv2: t2 = dinv*(a1@W2) -> tH ; a2 = relu(Agg(t2)+b2) -> hA
    gemm_mfma_kernel<<<gemm_blocks, blk, 0, stream>>>(hA, W2F, nullptr, dinv, tH, N, 128, 0);
    agg_pull_kernel<<<agg_blocks, blk, 0, stream>>>(rowp, colw, dinv, tH, b2, hA, N);
    // decoder: out = a2@Wo + bo -> d_out (fp32)
    gemm_mfma_kernel<<<gemm_blocks, blk, 0, stream>>>(hA, WoF, bo, nullptr, d_out, N, NC, 1);
}

// Round 15
// 211.991 us; speedup vs baseline: 1.1231x; 1.1231x over previous
//
#include <hip/hip_runtime.h>
#include <hip/hip_fp16.h>

// ---------------------------------------------------------------------------
// GCN: out = (relu(conv2(relu(conv1(x@We+be)))))@Wo + bo
// Fusion: t1 = (x@We+be)@W1 = x@Wcomb + bcomb (no nonlinearity between) —
// encoder GEMM + f32->f16 pass eliminated. GEMMs: fp16 MFMA, fp32 accum,
// epilogue v = (acc+bias)*rowscale. Conv t pre-scaled by dinv.
// Aggregation: CSR pull, 8-wide gather unroll, cached col loads.
// CSR build: dst-range buckets (RS=100) -> scan -> per-bucket LDS hist+fill.
// FIX r15: __syncthreads() between rowp-read and fillo-scatter phases in
// csr_from_bucket_kernel (race caused intermittent one-edge row shifts).
// ---------------------------------------------------------------------------

#define WS_ALIGN(x) (((x) + 255) & ~(size_t)255)
#define RS 100      // nodes per bucket
#define BCHUNK 8192 // edges per block in bucket pass

typedef _Float16 f16x8 __attribute__((ext_vector_type(8)));
typedef float f32x4 __attribute__((ext_vector_type(4)));

// Single block: detect int64 vs int32 edges; zero bfil counters.
__global__ void detect_zero_kernel(const unsigned* __restrict__ p, int* __restrict__ flag,
                                   unsigned* __restrict__ bfil, int nzero) {
    __shared__ int any;
    if (threadIdx.x == 0) any = 0;
    __syncthreads();
    int nz = 0;
    for (int i = threadIdx.x; i < 2048; i += blockDim.x)
        nz |= (p[2 * i + 1] != 0u) ? 1 : 0;
    if (nz) atomicOr(&any, 1);
    for (int i = threadIdx.x; i < nzero; i += blockDim.x) bfil[i] = 0u;
    __syncthreads();
    if (threadIdx.x == 0) *flag = (any == 0) ? 1 : 0;
}

// Bucket edges into nbuck dst-range buckets. Two passes over the block's edge
// chunk (2nd pass L2-hot): LDS count -> one global atomicAdd per bucket ->
// LDS-cursor placement.
__global__ __launch_bounds__(256) void bucket_kernel(
    const void* __restrict__ ep, const int* __restrict__ flag,
    unsigned* __restrict__ bkt, unsigned* __restrict__ bfill_pad,
    int E, int nbuck, int capB) {
    __shared__ unsigned lcnt[512];
    __shared__ unsigned gcur[512];
    const int tid = threadIdx.x;
    for (int i = tid; i < nbuck; i += 256) lcnt[i] = 0;
    __syncthreads();
    const int base = blockIdx.x * BCHUNK;
    const int end = min(base + BCHUNK, E);
    const int i64 = *flag;
    if (i64) {
        const long long* p = (const long long*)ep;
        for (int i = base + tid; i < end; i += 256) {
            int d = (int)p[(size_t)E + i];
            atomicAdd(&lcnt[d / RS], 1u);
        }
    } else {
        const int* p = (const int*)ep;
        for (int i = base + tid; i < end; i += 256) {
            int d = p[(size_t)E + i];
            atomicAdd(&lcnt[d / RS], 1u);
        }
    }
    __syncthreads();
    for (int i = tid; i < nbuck; i += 256)
        gcur[i] = atomicAdd(&bfill_pad[i << 4], lcnt[i]);
    __syncthreads();
    if (i64) {
        const long long* p = (const long long*)ep;
        for (int i = base + tid; i < end; i += 256) {
            int s = (int)p[i];
            int d = (int)p[(size_t)E + i];
            int part = d / RS;
            int ld = d - part * RS;
            unsigned pos = atomicAdd(&gcur[part], 1u);
            if (pos < (unsigned)capB)
                bkt[(size_t)part * capB + pos] = ((unsigned)ld << 24) | (unsigned)s;
        }
    } else {
        const int* p = (const int*)ep;
        for (int i = base + tid; i < end; i += 256) {
            int s = p[i];
            int d = p[(size_t)E + i];
            int part = d / RS;
            int ld = d - part * RS;
            unsigned pos = atomicAdd(&gcur[part], 1u);
            if (pos < (unsigned)capB)
                bkt[(size_t)part * capB + pos] = ((unsigned)ld << 24) | (unsigned)s;
        }
    }
}

// Exclusive scan of bucket counts -> ebase; rowp[n] = total.
__global__ __launch_bounds__(512) void bucket_scan_kernel(
    const unsigned* __restrict__ bfill_pad, unsigned* __restrict__ ebase,
    int* __restrict__ rowp, int nbuck, int capB, int n) {
    __shared__ unsigned lds[512];
    const int tid = threadIdx.x;
    unsigned v = 0;
    if (tid < nbuck) {
        v = bfill_pad[tid << 4];
        if (v > (unsigned)capB) v = capB;
    }
    lds[tid] = v;
    __syncthreads();
    for (int off = 1; off < 512; off <<= 1) {
        unsigned add = (tid >= off) ? lds[tid - off] : 0;
        __syncthreads();
        lds[tid] += add;
        __syncthreads();
    }
    if (tid < nbuck) ebase[tid] = lds[tid] - v;  // exclusive
    if (tid == 511) rowp[n] = (int)lds[511];
}

// One block per bucket: LDS hist -> rowp/dinv; then (after a barrier) scatter
// col into the bucket's contiguous CSR window.
__global__ __launch_bounds__(256) void csr_from_bucket_kernel(
    const unsigned* __restrict__ bkt, const unsigned* __restrict__ bfill_pad,
    const unsigned* __restrict__ ebase,
    int* __restrict__ rowp, float* __restrict__ dinv, int* __restrict__ col,
    int capB, int n) {
    __shared__ unsigned hist[RS];
    __shared__ int fillo[RS];
    const int p = blockIdx.x;
    const int tid = threadIdx.x;
    for (int i = tid; i < RS; i += 256) hist[i] = 0;
    __syncthreads();
    unsigned cnt = bfill_pad[p << 4];
    if (cnt > (unsigned)capB) cnt = capB;
    const unsigned* bp = bkt + (size_t)p * capB;
    for (unsigned e = tid; e < cnt; e += 256)
        atomicAdd(&hist[bp[e] >> 24], 1u);
    __syncthreads();
    if (tid == 0) {
        int run = (int)ebase[p];
        for (int i = 0; i < RS; ++i) { fillo[i] = run; run += (int)hist[i]; }
    }
    __syncthreads();
    const int lo = p * RS;
    for (int i = tid; i < RS; i += 256) {
        int node = lo + i;
        if (node < n) {
            rowp[node] = fillo[i];
            dinv[node] = rsqrtf((float)(hist[i] + 1u));
        }
    }
    __syncthreads();  // FIX: all fillo reads (rowp) complete before scatter mutates fillo
    for (unsigned e = tid; e < cnt; e += 256) {
        unsigned u = bp[e];
        int ld = (int)(u >> 24);
        int pos = atomicAdd(&fillo[ld], 1);
        col[pos] = (int)(u & 0xFFFFFFu);
    }
}

// Wcomb = We@W1 (fp32, 128x128), bcomb = be@W1. 64 blocks x 256 threads.
__global__ __launch_bounds__(256) void wcomb_kernel(
    const float* __restrict__ We, const float* __restrict__ W1,
    const float* __restrict__ be, float* __restrict__ Wcomb,
    float* __restrict__ bcomb) {
    int t = blockIdx.x * 256 + threadIdx.x;  // 16384 = 128*128
    int r = t >> 7, c = t & 127;
    float s = 0.f;
    for (int k = 0; k < 128; ++k) s = fmaf(We[r * 128 + k], W1[k * 128 + c], s);
    Wcomb[t] = s;
    if (t < 128) {
        float b = 0.f;
        for (int k = 0; k < 128; ++k) b = fmaf(be[k], W1[k * 128 + t], b);
        bcomb[t] = b;
    }
}

// Fragment-ready W for 3 matrices in one launch:
// blocks 0-7: Wcomb(128); 8-15: W2(128); 16-19: Wo(ncol=nco).
__global__ __launch_bounds__(256) void wfrag3_kernel(
    const float* __restrict__ Wa, __half* __restrict__ WaF,
    const float* __restrict__ Wb, __half* __restrict__ WbF,
    const float* __restrict__ Wc, __half* __restrict__ WcF, int nco) {
    const float* W;
    __half* Wf;
    int ncol, t;
    if (blockIdx.x < 8)       { W = Wa; Wf = WaF; ncol = 128; t = blockIdx.x * 256 + threadIdx.x; }
    else if (blockIdx.x < 16) { W = Wb; Wf = WbF; ncol = 128; t = (blockIdx.x - 8) * 256 + threadIdx.x; }
    else                      { W = Wc; Wf = WcF; ncol = nco; t = (blockIdx.x - 16) * 256 + threadIdx.x; }
    int total = (ncol >> 4) * 4 * 64;
    if (t >= total) return;
    int lane = t & 63;
    int ks = (t >> 6) & 3;
    int c0 = t >> 8;
    int colw = c0 * 16 + (lane & 15);
    int k0 = ks * 32 + ((lane >> 4) << 3);
    __half vals[8];
#pragma unroll
    for (int j = 0; j < 8; ++j) vals[j] = __float2half(W[(size_t)(k0 + j) * ncol + colw]);
    *(uint4*)(Wf + (size_t)t * 8) = *(uint4*)vals;
}

// out[i][:] = relu( bias + dinv[i]*( t_s[i][:] + sum_j t_s[col[j]][:] ) )
// t_s fp16 pre-scaled by dinv[row]. 32 lanes/node, 8-wide gather unroll.
__global__ __launch_bounds__(256) void agg_pull_kernel(
    const int* __restrict__ rowp, const int* __restrict__ col,
    const float* __restrict__ dinv, const __half* __restrict__ t,
    const float* __restrict__ bias, __half* __restrict__ out, int n) {
    int node = blockIdx.x * 8 + (threadIdx.x >> 5);
    int lane = threadIdx.x & 31;
    if (node >= n) return;
    const uint2* T = (const uint2*)t;
    int j0 = rowp[node], j1 = rowp[node + 1];
    float dn = dinv[node];

    uint2 sraw = T[(size_t)node * 32 + lane];
    float2 s01 = __half22float2(*(const __half2*)&sraw.x);
    float2 s23 = __half22float2(*(const __half2*)&sraw.y);
    float4 acc = make_float4(s01.x, s01.y, s23.x, s23.y);

    int j = j0;
    for (; j + 7 < j1; j += 8) {
        int c[8];
        uint2 r[8];
#pragma unroll
        for (int k = 0; k < 8; ++k) c[k] = col[j + k];
#pragma unroll
        for (int k = 0; k < 8; ++k) r[k] = T[(size_t)c[k] * 32 + lane];
#pragma unroll
        for (int k = 0; k < 8; ++k) {
            float2 f01 = __half22float2(*(const __half2*)&r[k].x);
            float2 f23 = __half22float2(*(const __half2*)&r[k].y);
            acc.x += f01.x; acc.y += f01.y; acc.z += f23.x; acc.w += f23.y;
        }
    }
    for (; j + 3 < j1; j += 4) {
        int c[4];
        uint2 r[4];
#pragma unroll
        for (int k = 0; k < 4; ++k) c[k] = col[j + k];
#pragma unroll
        for (int k = 0; k < 4; ++k) r[k] = T[(size_t)c[k] * 32 + lane];
#pragma unroll
        for (int k = 0; k < 4; ++k) {
            float2 f01 = __half22float2(*(const __half2*)&r[k].x);
            float2 f23 = __half22float2(*(const __half2*)&r[k].y);
            acc.x += f01.x; acc.y += f01.y; acc.z += f23.x; acc.w += f23.y;
        }
    }
    for (; j < j1; ++j) {
        int c = col[j];
        uint2 raw = T[(size_t)c * 32 + lane];
        float2 f01 = __half22float2(*(const __half2*)&raw.x);
        float2 f23 = __half22float2(*(const __half2*)&raw.y);
        acc.x += f01.x; acc.y += f01.y; acc.z += f23.x; acc.w += f23.y;
    }

    float4 b = ((const float4*)bias)[lane];
    float ox = fmaxf(fmaf(acc.x, dn, b.x), 0.f);
    float oy = fmaxf(fmaf(acc.y, dn, b.y), 0.f);
    float oz = fmaxf(fmaf(acc.z, dn, b.z), 0.f);
    float ow = fmaxf(fmaf(acc.w, dn, b.w), 0.f);
    __half2 h01 = __floats2half2_rn(ox, oy);
    __half2 h23 = __floats2half2_rn(oz, ow);
    uint2 packed;
    packed.x = *(unsigned*)&h01;
    packed.y = *(unsigned*)&h23;
    ((uint2*)(out + (size_t)node * 128))[lane] = packed;
}

__device__ __forceinline__ f16x8 frag_from_f32(const float* p) {
    float4 u = *(const float4*)p;
    float4 v = *(const float4*)(p + 4);
    f16x8 r;
    r[0] = (_Float16)u.x; r[1] = (_Float16)u.y; r[2] = (_Float16)u.z; r[3] = (_Float16)u.w;
    r[4] = (_Float16)v.x; r[5] = (_Float16)v.y; r[6] = (_Float16)v.z; r[7] = (_Float16)v.w;
    return r;
}

// C[n,ncol] = A[n,128] @ W[128,ncol]; epilogue v=(acc+bias)*rowscale.
// a_fp32: A is fp32 (converted to frags in-kernel), else fp16.
__global__ __launch_bounds__(256) void gemm_mfma_kernel(
    const void* __restrict__ A, const __half* __restrict__ Wf,
    const float* __restrict__ bias, const float* __restrict__ rowscale,
    void* __restrict__ C, int n, int ncol, int a_fp32, int c_fp32) {
    const int wave = threadIdx.x >> 6;
    const int lane = threadIdx.x & 63;
    const int row0 = blockIdx.x * 64 + wave * 16;
    int ar = row0 + (lane & 15);
    if (ar >= n) ar = n - 1;
    const int koff = (lane >> 4) << 3;
    f16x8 a0, a1, a2, a3;
    if (a_fp32) {
        const float* ab = (const float*)A + (size_t)ar * 128 + koff;
        a0 = frag_from_f32(ab);
        a1 = frag_from_f32(ab + 32);
        a2 = frag_from_f32(ab + 64);
        a3 = frag_from_f32(ab + 96);
    } else {
        const __half* ab = (const __half*)A + (size_t)ar * 128 + koff;
        a0 = *(const f16x8*)(ab);
        a1 = *(const f16x8*)(ab + 32);
        a2 = *(const f16x8*)(ab + 64);
        a3 = *(const f16x8*)(ab + 96);
    }
    const int ncc = ncol >> 4;
    const int cic = lane & 15;
    const int rbase = (lane >> 4) << 2;
    float rs[4];
#pragma unroll
    for (int r = 0; r < 4; ++r) {
        int row = row0 + rbase + r;
        rs[r] = (rowscale && row < n) ? rowscale[row] : 1.f;
    }
    for (int c0 = 0; c0 < ncc; ++c0) {
        const f16x8* wf = (const f16x8*)Wf + (size_t)c0 * 256 + lane;
        f32x4 acc = {0.f, 0.f, 0.f, 0.f};
        acc = __builtin_amdgcn_mfma_f32_16x16x32_f16(a0, wf[0],   acc, 0, 0, 0);
        acc = __builtin_amdgcn_mfma_f32_16x16x32_f16(a1, wf[64],  acc, 0, 0, 0);
        acc = __builtin_amdgcn_mfma_f32_16x16x32_f16(a2, wf[128], acc, 0, 0, 0);
        acc = __builtin_amdgcn_mfma_f32_16x16x32_f16(a3, wf[192], acc, 0, 0, 0);
        int colc = (c0 << 4) + cic;
        float bv = bias ? bias[colc] : 0.f;
#pragma unroll
        for (int r = 0; r < 4; ++r) {
            int row = row0 + rbase + r;
            if (row < n) {
                float v = (acc[r] + bv) * rs[r];
                if (c_fp32) ((float*)C)[(size_t)row * ncol + colc] = v;
                else        ((__half*)C)[(size_t)row * ncol + colc] = __float2half(v);
            }
        }
    }
}

extern "C" void kernel_launch(void* const* d_in, const int* in_sizes, int n_in,
                              void* d_out, int out_size, void* d_ws, size_t ws_size,
                              hipStream_t stream) {
    const float* x  = (const float*)d_in[0];
    const void*  ei = d_in[1];
    const float* We = (const float*)d_in[2];
    const float* be = (const float*)d_in[3];
    const float* W1 = (const float*)d_in[4];
    const float* b1 = (const float*)d_in[5];
    const float* W2 = (const float*)d_in[6];
    const float* b2 = (const float*)d_in[7];
    const float* Wo = (const float*)d_in[8];
    const float* bo = (const float*)d_in[9];
    const int N = in_sizes[0] / 128;
    const int E = in_sizes[1] / 2;
    const int NC = in_sizes[9];                 // NUM_CLASS = 64
    const int nbuck = (N + RS - 1) / RS;        // 500 for N=50000 (<=512)
    const int capB = (E + nbuck - 1) / nbuck + 512;

    char* ws = (char*)d_ws;
    size_t off = 0;
    int*      flag = (int*)(ws + off);      off += 256;
    unsigned* bfil = (unsigned*)(ws + off); off += WS_ALIGN((size_t)nbuck * 64);
    unsigned* ebas = (unsigned*)(ws + off); off += WS_ALIGN((size_t)nbuck * 4);
    unsigned* bkt  = (unsigned*)(ws + off); off += WS_ALIGN((size_t)nbuck * capB * 4);
    float*    dinv = (float*)(ws + off);    off += WS_ALIGN((size_t)N * 4);
    int*      rowp = (int*)(ws + off);      off += WS_ALIGN((size_t)(N + 1) * 4);
    int*      colw = (int*)(ws + off);      off += WS_ALIGN((size_t)E * 4);
    float*    Wcmb = (float*)(ws + off);    off += WS_ALIGN((size_t)128 * 128 * 4);
    float*    bcmb = (float*)(ws + off);    off += WS_ALIGN((size_t)128 * 4);
    __half*   WcF  = (__half*)(ws + off);   off += WS_ALIGN((size_t)128 * 128 * 2);
    __half*   W2F  = (__half*)(ws + off);   off += WS_ALIGN((size_t)128 * 128 * 2);
    __half*   WoF  = (__half*)(ws + off);   off += WS_ALIGN((size_t)128 * 64 * 2);
    __half*   hA   = (__half*)(ws + off);   off += WS_ALIGN((size_t)N * 128 * 2);
    __half*   tH   = (__half*)(ws + off);   off += WS_ALIGN((size_t)N * 128 * 2);

    const int nb_bucket = (E + BCHUNK - 1) / BCHUNK;
    dim3 blk(256);

    // CSR build via buckets
    detect_zero_kernel<<<1, 256, 0, stream>>>((const unsigned*)ei, flag, bfil, nbuck * 16);
    bucket_kernel<<<nb_bucket, blk, 0, stream>>>(ei, flag, bkt, bfil, E, nbuck, capB);
    bucket_scan_kernel<<<1, 512, 0, stream>>>(bfil, ebas, rowp, nbuck, capB, N);
    csr_from_bucket_kernel<<<nbuck, blk, 0, stream>>>(bkt, bfil, ebas, rowp, dinv, colw, capB, N);

    // Wcomb = We@W1, bcomb = be@W1; then fp16 fragments for Wcomb/W2/Wo
    wcomb_kernel<<<64, blk, 0, stream>>>(We, W1, be, Wcmb, bcmb);
    wfrag3_kernel<<<20, blk, 0, stream>>>(Wcmb, WcF, W2, W2F, Wo, WoF, NC);

    const int gemm_blocks = (N + 63) / 64;
    const int agg_blocks = (N + 7) / 8;

    // conv1: t1 = dinv*(x@Wcomb + bcomb) -> tH ; a1 = relu(Agg+b1) -> hA
    gemm_mfma_kernel<<<gemm_blocks, blk, 0, stream>>>(x, WcF, bcmb, dinv, tH, N, 128, 1, 0);
    agg_pull_kernel<<<agg_blocks, blk, 0, stream>>>(rowp, colw, dinv, tH, b1, hA, N);
    // conv2: t2 = dinv*(a1@W2) -> tH ; a2 = relu(Agg+b2) -> hA
    gemm_mfma_kernel<<<gemm_blocks, blk, 0, stream>>>(hA, W2F, nullptr, dinv, tH, N, 128, 0, 0);
    agg_pull_kernel<<<agg_blocks, blk, 0, stream>>>(rowp, colw, dinv, tH, b2, hA, N);
    // decoder: out = a2@Wo + bo -> d_out (fp32)
    gemm_mfma_kernel<<<gemm_blocks, blk, 0, stream>>>(hA, WoF, bo, nullptr, d_out, N, NC, 0, 1);
}